// Round 5
// baseline (35.106 us; speedup 1.0000x reference)
//
#include <hip/hip_runtime.h>
#include <math.h>

#define NIMG 131072
#define NBLK 512   // k_main grid: 512 blocks x 256 threads = 1 thread per image

// ws layout (floats): [0..1023] partial[1024] (sum,sumsq per k_main block)

__device__ __forceinline__ float med3f(float a, float b, float c) {
  return __builtin_amdgcn_fmed3f(a, b, c);
}
__device__ __forceinline__ float min3f(float a, float b, float c) { return fminf(fminf(a, b), c); }
__device__ __forceinline__ float max3f(float a, float b, float c) { return fmaxf(fmaxf(a, b), c); }

__device__ __forceinline__ float rdlane(float v, int lane) {
  return __uint_as_float(__builtin_amdgcn_readlane(__float_as_uint(v), lane));
}

// ---------------------------------------------------------------------------
// Fold shift + FC into W'[c] for pixel p (math validated on HW in R1/R3/R4).
__device__ __forceinline__ void fold_weights(int p, const float* __restrict__ fc_w,
                                             float sx, float sy, float* __restrict__ w8) {
  const int y = p >> 4, x = p & 15;
  const int dY = (sy > 1.0f) ? 2 : 1;
  const int dX = (sx > 1.0f) ? 2 : 1;
  const float wy1 = (float)dY - sy, wy0 = 1.0f - wy1;
  const float wx1 = (float)dX - sx, wx0 = 1.0f - wx1;
  const int   iys[2] = { y + dY - 1, y + dY };
  const float wys[2] = { wy1, wy0 };
  const int   jxs[2] = { x + dX - 1, x + dX };
  const float wxs[2] = { wx1, wx0 };
  #pragma unroll
  for (int c = 0; c < 8; ++c) {
    float acc = 0.0f;
    #pragma unroll
    for (int a = 0; a < 2; ++a) {
      if (iys[a] < 0 || iys[a] >= 8) continue;
      #pragma unroll
      for (int b = 0; b < 2; ++b) {
        if (jxs[b] < 0 || jxs[b] >= 16) continue;
        acc += wys[a] * wxs[b] * fc_w[c * 128 + iys[a] * 16 + jxs[b]];
      }
    }
    w8[c] = acc;
  }
}

// ---------------------------------------------------------------------------
// K1: one thread per image. Medians in registers. Folded weights live in 16
// VGPRs per wave (lane l holds the 8 weights of pixels 2l and 2l+1); the
// fully-unrolled dot fetches them with v_readlane (constant lane) -> zero DS
// traffic, zero lgkmcnt stalls. Writes RAW dots to out, (sum,sumsq) to ws.
__global__ __launch_bounds__(256, 2) void k_main(const float* __restrict__ x,
                                                 const float* __restrict__ fcw,
                                                 const float* __restrict__ xs,
                                                 const float* __restrict__ ys,
                                                 float* __restrict__ out,
                                                 float* __restrict__ partial) {
  __shared__ float sred[8];
  const int tid = threadIdx.x;
  const int w = tid >> 6, l = tid & 63;
  const int img = blockIdx.x * 256 + tid;
  const float* __restrict__ xi = x + (size_t)img * 128;

  // input prologue loads (independent of the weight fold)
  float rows[4][16];
  #pragma unroll
  for (int rr = 0; rr < 2; ++rr)
    #pragma unroll
    for (int q = 0; q < 4; ++q)
      *(float4*)&rows[rr][q * 4] = *(const float4*)&xi[rr * 16 + q * 4];

  // wave-resident folded weights: lane l, regs 0..7 -> pixel 2l, regs 8..15 -> pixel 2l+1
  const float sx = xs[0] + 0.5f, sy = ys[0] + 0.5f;
  float wpair[16];
  fold_weights(2 * l,     fcw, sx, sy, &wpair[0]);
  fold_weights(2 * l + 1, fcw, sx, sy, &wpair[8]);

  float acc[8];
  #pragma unroll
  for (int c = 0; c < 8; ++c) acc[c] = 0.0f;
  float ssum = 0.0f, ssq = 0.0f;

  #pragma unroll
  for (int r = 0; r < 8; ++r) {
    if (r < 6) {
      #pragma unroll
      for (int q = 0; q < 4; ++q)
        *(float4*)&rows[(r + 2) & 3][q * 4] = *(const float4*)&xi[(r + 2) * 16 + q * 4];
    }
    // vertical sort3 per column (zero rows outside [0,7])
    float lo[16], mi[16], hi[16];
    #pragma unroll
    for (int c = 0; c < 16; ++c) {
      const float a = (r == 0) ? 0.0f : rows[(r - 1) & 3][c];
      const float b = rows[r & 3][c];
      const float d = (r == 7) ? 0.0f : rows[(r + 1) & 3][c];
      lo[c] = min3f(a, b, d);
      mi[c] = med3f(a, b, d);
      hi[c] = max3f(a, b, d);
    }
    // horizontal combine (zero cols outside [0,15]) + stats + dot
    #pragma unroll
    for (int j = 0; j < 16; ++j) {
      const float l0 = (j == 0) ? 0.0f : lo[j - 1];
      const float l2 = (j == 15) ? 0.0f : lo[j + 1];
      const float m0 = (j == 0) ? 0.0f : mi[j - 1];
      const float m2 = (j == 15) ? 0.0f : mi[j + 1];
      const float h0 = (j == 0) ? 0.0f : hi[j - 1];
      const float h2 = (j == 15) ? 0.0f : hi[j + 1];
      const float mx = max3f(l0, lo[j], l2);
      const float md = med3f(m0, mi[j], m2);
      const float mn = min3f(h0, hi[j], h2);
      const float med = med3f(mx, md, mn);  // exact lower-median of 9
      ssum += med;
      ssq = fmaf(med, med, ssq);
      const int p    = r * 16 + j;      // compile-time
      const int src  = p >> 1;          // lane immediate
      const int base = (p & 1) << 3;    // static reg index
      acc[0] = fmaf(med, rdlane(wpair[base + 0], src), acc[0]);
      acc[1] = fmaf(med, rdlane(wpair[base + 1], src), acc[1]);
      acc[2] = fmaf(med, rdlane(wpair[base + 2], src), acc[2]);
      acc[3] = fmaf(med, rdlane(wpair[base + 3], src), acc[3]);
      acc[4] = fmaf(med, rdlane(wpair[base + 4], src), acc[4]);
      acc[5] = fmaf(med, rdlane(wpair[base + 5], src), acc[5]);
      acc[6] = fmaf(med, rdlane(wpair[base + 6], src), acc[6]);
      acc[7] = fmaf(med, rdlane(wpair[base + 7], src), acc[7]);
    }
  }

  // raw dots to out (scaled in k_scale)
  float4* o4 = (float4*)&out[(size_t)img * 8];
  o4[0] = make_float4(acc[0], acc[1], acc[2], acc[3]);
  o4[1] = make_float4(acc[4], acc[5], acc[6], acc[7]);

  // per-block stats
  #pragma unroll
  for (int off = 32; off; off >>= 1) {
    ssum += __shfl_xor(ssum, off, 64);
    ssq  += __shfl_xor(ssq,  off, 64);
  }
  if (l == 0) { sred[w] = ssum; sred[4 + w] = ssq; }
  __syncthreads();
  if (tid == 0) partial[2 * blockIdx.x]     = (sred[0] + sred[1]) + (sred[2] + sred[3]);
  if (tid == 1) partial[2 * blockIdx.x + 1] = (sred[4] + sred[5]) + (sred[6] + sred[7]);
}

// ---------------------------------------------------------------------------
// K2: every block redundantly reduces partial[1024] (L2-hot, deterministic),
// recomputes the W' fold for per-class sums, then scales its slice of out
// in place: out = alpha*dot + (beta*wsum[c] + fcb[c]).
__global__ __launch_bounds__(256) void k_scale(float* __restrict__ out,
                                               const float* __restrict__ partial,
                                               const float* __restrict__ fcw,
                                               const float* __restrict__ xs,
                                               const float* __restrict__ ys,
                                               const float* __restrict__ fcb,
                                               const float* __restrict__ bnw,
                                               const float* __restrict__ bnb) {
  __shared__ float sred[8];
  __shared__ float wred[4][8];
  __shared__ float fin[2];
  const int tid = threadIdx.x;
  const int w = tid >> 6, l = tid & 63;

  float s = partial[2 * tid]     + partial[2 * (tid + 256)];
  float q = partial[2 * tid + 1] + partial[2 * (tid + 256) + 1];
  #pragma unroll
  for (int off = 32; off; off >>= 1) {
    s += __shfl_xor(s, off, 64);
    q += __shfl_xor(q, off, 64);
  }

  float v[8];
  if (tid < 128) {
    fold_weights(tid, fcw, xs[0] + 0.5f, ys[0] + 0.5f, v);
  } else {
    #pragma unroll
    for (int c = 0; c < 8; ++c) v[c] = 0.0f;
  }
  #pragma unroll
  for (int c = 0; c < 8; ++c) {
    #pragma unroll
    for (int off = 32; off; off >>= 1) v[c] += __shfl_xor(v[c], off, 64);
  }

  if (l == 0) {
    sred[w] = s; sred[4 + w] = q;
    #pragma unroll
    for (int c = 0; c < 8; ++c) wred[w][c] = v[c];
  }
  __syncthreads();
  if (tid == 0) {
    const float S = (sred[0] + sred[1]) + (sred[2] + sred[3]);
    const float Q = (sred[4] + sred[5]) + (sred[6] + sred[7]);
    const float N = 16777216.0f;  // 131072*128
    const float mm = S / N;
    const float vv = Q / N - mm * mm;
    const float a = bnw[0] / sqrtf(vv + 1e-5f);
    fin[0] = a;
    fin[1] = bnb[0] - mm * a;
  }
  __syncthreads();
  const float alpha = fin[0], beta = fin[1];

  const int i = blockIdx.x * 256 + tid;  // 262144 float4 covering [131072][8]
  const int g = (i & 1) ? 4 : 0;
  float4 cv;
  cv.x = fmaf(beta, (wred[0][g + 0] + wred[1][g + 0]) + (wred[2][g + 0] + wred[3][g + 0]), fcb[g + 0]);
  cv.y = fmaf(beta, (wred[0][g + 1] + wred[1][g + 1]) + (wred[2][g + 1] + wred[3][g + 1]), fcb[g + 1]);
  cv.z = fmaf(beta, (wred[0][g + 2] + wred[1][g + 2]) + (wred[2][g + 2] + wred[3][g + 2]), fcb[g + 2]);
  cv.w = fmaf(beta, (wred[0][g + 3] + wred[1][g + 3]) + (wred[2][g + 3] + wred[3][g + 3]), fcb[g + 3]);

  float4* o4 = (float4*)out;
  float4 ov = o4[i];
  ov.x = fmaf(alpha, ov.x, cv.x);
  ov.y = fmaf(alpha, ov.y, cv.y);
  ov.z = fmaf(alpha, ov.z, cv.z);
  ov.w = fmaf(alpha, ov.w, cv.w);
  o4[i] = ov;
}

// ---------------------------------------------------------------------------
extern "C" void kernel_launch(void* const* d_in, const int* in_sizes, int n_in,
                              void* d_out, int out_size, void* d_ws, size_t ws_size,
                              hipStream_t stream) {
  const float* x   = (const float*)d_in[0];
  const float* bnw = (const float*)d_in[1];
  const float* bnb = (const float*)d_in[2];
  const float* xs  = (const float*)d_in[3];
  const float* ys  = (const float*)d_in[4];
  const float* fcw = (const float*)d_in[5];
  const float* fcb = (const float*)d_in[6];
  float* out = (float*)d_out;
  float* ws  = (float*)d_ws;

  float* partial = ws;  // 1024 floats

  hipLaunchKernelGGL(k_main,  dim3(NBLK), dim3(256), 0, stream, x, fcw, xs, ys, out, partial);
  hipLaunchKernelGGL(k_scale, dim3(1024), dim3(256), 0, stream, out, partial, fcw, xs, ys, fcb, bnw, bnb);
}